// Round 2
// baseline (1534.797 us; speedup 1.0000x reference)
//
#include <hip/hip_runtime.h>
#include <math.h>

#define KDIM 8192
#define THREADS 256
#define RPB 16              // rows per block (4 per wave)
#define CHUNK 256           // k-values staged per chunk
#define NCHUNK 32           // KDIM / CHUNK
#define CHUNK_F4 1536       // CHUNK * 24 floats / 4
#define NKQ 128             // KDIM / 64 (k-groups per lane)

__global__ __launch_bounds__(THREADS, 3)
void mhc_coeffs_kernel(const float* __restrict__ x,
                       const float* __restrict__ phi,
                       const float* __restrict__ bvec,
                       const float* __restrict__ a_pre,
                       const float* __restrict__ a_post,
                       const float* __restrict__ a_res,
                       float* __restrict__ out, int nrows)
{
    // phi chunk staging, double-buffered. Row k (24 floats = 96 B) stored at
    // byte (k*96 + j*16) ^ ((k&7)<<4)  -- XOR swizzle, bijective per 128B
    // window, makes stride-1-row ds_read_b128 across lanes conflict-free.
    __shared__ float4 ldsA[CHUNK_F4];
    __shared__ float4 ldsB[CHUNK_F4];

    const int t    = threadIdx.x;
    const int lane = t & 63;
    const int rowbase = blockIdx.x * RPB + (t >> 6) * 4;

    float acc[4][25];
#pragma unroll
    for (int r = 0; r < 4; ++r)
#pragma unroll
        for (int j = 0; j < 25; ++j) acc[r][j] = 0.f;

    // staging write slots (float4 index), fixed per thread: flat slot i*256+t
    int wslot[6];
#pragma unroll
    for (int i = 0; i < 6; ++i) {
        const int t16 = i * 256 + t;          // 16B unit within chunk
        const int row = t16 / 6;              // phi row this 16B belongs to
        wslot[i] = ((t16 * 16) ^ ((row & 7) << 4)) >> 4;
    }

    // read slots (float4 index) for q=0; add q*384 per q (XOR-safe: q*6144B
    // only touches bits >= 11, swizzle lives in bits 4..6)
    int rbase[6];
#pragma unroll
    for (int j = 0; j < 6; ++j)
        rbase[j] = (((lane * 96) + j * 16) ^ ((lane & 7) << 4)) >> 4;

    const float4* phi4 = (const float4*)phi;

    const float* xr0 = x + (size_t)(rowbase + 0) * KDIM + lane;
    const float* xr1 = x + (size_t)(rowbase + 1) * KDIM + lane;
    const float* xr2 = x + (size_t)(rowbase + 2) * KDIM + lane;
    const float* xr3 = x + (size_t)(rowbase + 3) * KDIM + lane;

    // ---- prologue: stage chunk 0, prefetch first x ----
    float4 s0 = phi4[0 * 256 + t];
    float4 s1 = phi4[1 * 256 + t];
    float4 s2 = phi4[2 * 256 + t];
    float4 s3 = phi4[3 * 256 + t];
    float4 s4 = phi4[4 * 256 + t];
    float4 s5 = phi4[5 * 256 + t];
    float xa0 = xr0[0], xa1 = xr1[0], xa2 = xr2[0], xa3 = xr3[0];
    ldsA[wslot[0]] = s0; ldsA[wslot[1]] = s1; ldsA[wslot[2]] = s2;
    ldsA[wslot[3]] = s3; ldsA[wslot[4]] = s4; ldsA[wslot[5]] = s5;
    __syncthreads();

    float4* cur = ldsA;
    float4* nxt = ldsB;

    for (int c = 0; c < NCHUNK; ++c) {
        const bool more = (c + 1 < NCHUNK);
        if (more) {  // issue next chunk's staging loads early (latency hides under FMAs)
            const float4* pc = phi4 + (size_t)(c + 1) * CHUNK_F4;
            s0 = pc[t];        s1 = pc[256 + t];  s2 = pc[512 + t];
            s3 = pc[768 + t];  s4 = pc[1024 + t]; s5 = pc[1280 + t];
        }
#pragma unroll
        for (int q = 0; q < 4; ++q) {
            const int kq = c * 4 + q;
            // prefetch next kq's x (one step ahead)
            float xb0 = 0.f, xb1 = 0.f, xb2 = 0.f, xb3 = 0.f;
            if (kq + 1 < NKQ) {
                const int o = (kq + 1) * 64;
                xb0 = xr0[o]; xb1 = xr1[o]; xb2 = xr2[o]; xb3 = xr3[o];
            }
#pragma unroll
            for (int j = 0; j < 6; ++j) {
                const float4 p = cur[rbase[j] + q * 384];
                const int jb = j * 4;
                acc[0][jb + 0] = fmaf(xa0, p.x, acc[0][jb + 0]);
                acc[0][jb + 1] = fmaf(xa0, p.y, acc[0][jb + 1]);
                acc[0][jb + 2] = fmaf(xa0, p.z, acc[0][jb + 2]);
                acc[0][jb + 3] = fmaf(xa0, p.w, acc[0][jb + 3]);
                acc[1][jb + 0] = fmaf(xa1, p.x, acc[1][jb + 0]);
                acc[1][jb + 1] = fmaf(xa1, p.y, acc[1][jb + 1]);
                acc[1][jb + 2] = fmaf(xa1, p.z, acc[1][jb + 2]);
                acc[1][jb + 3] = fmaf(xa1, p.w, acc[1][jb + 3]);
                acc[2][jb + 0] = fmaf(xa2, p.x, acc[2][jb + 0]);
                acc[2][jb + 1] = fmaf(xa2, p.y, acc[2][jb + 1]);
                acc[2][jb + 2] = fmaf(xa2, p.z, acc[2][jb + 2]);
                acc[2][jb + 3] = fmaf(xa2, p.w, acc[2][jb + 3]);
                acc[3][jb + 0] = fmaf(xa3, p.x, acc[3][jb + 0]);
                acc[3][jb + 1] = fmaf(xa3, p.y, acc[3][jb + 1]);
                acc[3][jb + 2] = fmaf(xa3, p.z, acc[3][jb + 2]);
                acc[3][jb + 3] = fmaf(xa3, p.w, acc[3][jb + 3]);
            }
            acc[0][24] = fmaf(xa0, xa0, acc[0][24]);
            acc[1][24] = fmaf(xa1, xa1, acc[1][24]);
            acc[2][24] = fmaf(xa2, xa2, acc[2][24]);
            acc[3][24] = fmaf(xa3, xa3, acc[3][24]);
            xa0 = xb0; xa1 = xb1; xa2 = xb2; xa3 = xb3;
        }
        if (more) {
            nxt[wslot[0]] = s0; nxt[wslot[1]] = s1; nxt[wslot[2]] = s2;
            nxt[wslot[3]] = s3; nxt[wslot[4]] = s4; nxt[wslot[5]] = s5;
            float4* tmp = cur; cur = nxt; nxt = tmp;
            __syncthreads();
        }
    }

    // ---- k-reduction across 64 lanes (butterfly) ----
#pragma unroll
    for (int r = 0; r < 4; ++r)
#pragma unroll
        for (int j = 0; j < 25; ++j) {
            float v = acc[r][j];
            v += __shfl_xor(v, 1);
            v += __shfl_xor(v, 2);
            v += __shfl_xor(v, 4);
            v += __shfl_xor(v, 8);
            v += __shfl_xor(v, 16);
            v += __shfl_xor(v, 32);
            acc[r][j] = v;
        }

    // ---- epilogue: lane = r*16 + (i*4+j) of the 4x4 sinkhorn matrix ----
    const int r = lane >> 4;
    const int e = lane & 15;
    const int row = rowbase + r;

    float rs[25];
#pragma unroll
    for (int j = 0; j < 25; ++j)
        rs[j] = (r == 0) ? acc[0][j] : (r == 1) ? acc[1][j] : (r == 2) ? acc[2][j] : acc[3][j];

    const float invr = 1.0f / sqrtf(rs[24] * (1.0f / (float)KDIM) + 1e-6f);

    // res logit for this lane's element
    float dres = rs[8];
#pragma unroll
    for (int m = 1; m < 16; ++m) dres = (e == m) ? rs[8 + m] : dres;
    const float lg = fmaf(dres * invr, a_res[0], bvec[8 + e]);

    // softmax over j (lanes ^1, ^2 within 4-lane row group)
    float mx = fmaxf(lg, __shfl_xor(lg, 1));
    mx = fmaxf(mx, __shfl_xor(mx, 2));
    const float ex = expf(lg - mx);
    float sm = ex + __shfl_xor(ex, 1);
    sm += __shfl_xor(sm, 2);
    float mat = ex / sm + 1e-6f;

    // col-normalize, then 7x (row-norm; col-norm)
    float cs = mat + __shfl_xor(mat, 4);
    cs += __shfl_xor(cs, 8);
    mat = mat / (cs + 1e-6f);
#pragma unroll
    for (int it = 0; it < 7; ++it) {
        float rsum = mat + __shfl_xor(mat, 1);
        rsum += __shfl_xor(rsum, 2);
        mat = mat / (rsum + 1e-6f);
        float csum = mat + __shfl_xor(mat, 4);
        csum += __shfl_xor(csum, 8);
        mat = mat / (csum + 1e-6f);
    }
    out[(size_t)nrows * 8 + (size_t)row * 16 + e] = mat;

    if (e < 8) {
        float dpp = rs[0];
#pragma unroll
        for (int m = 1; m < 8; ++m) dpp = (e == m) ? rs[m] : dpp;
        if (e < 4) {
            const float z = fmaf(dpp * invr, a_pre[0], bvec[e]);
            out[(size_t)row * 4 + e] = 1.0f / (1.0f + expf(-z)) + 0.01f;
        } else {
            const float z = fmaf(dpp * invr, a_post[0], bvec[e]);
            out[(size_t)nrows * 4 + (size_t)row * 4 + (e - 4)] = 2.0f / (1.0f + expf(-z));
        }
    }
}

extern "C" void kernel_launch(void* const* d_in, const int* in_sizes, int n_in,
                              void* d_out, int out_size, void* d_ws, size_t ws_size,
                              hipStream_t stream) {
    const float* x     = (const float*)d_in[0];
    const float* phi   = (const float*)d_in[1];
    const float* bvec  = (const float*)d_in[2];
    const float* apre  = (const float*)d_in[3];
    const float* apost = (const float*)d_in[4];
    const float* ares  = (const float*)d_in[5];
    float* out = (float*)d_out;

    const int nrows  = in_sizes[0] / KDIM;     // 16384
    const int blocks = nrows / RPB;            // 1024

    mhc_coeffs_kernel<<<blocks, THREADS, 0, stream>>>(x, phi, bvec, apre, apost, ares, out, nrows);
}